// Round 1
// baseline (1097.890 us; speedup 1.0000x reference)
//
#include <hip/hip_runtime.h>

#define NB   8192
#define BATCH 2
#define FIN  128
#define FO   64
#define SPLIT 4

typedef _Float16 f16;
typedef _Float16 f16x4 __attribute__((ext_vector_type(4)));
typedef float    f32x4 __attribute__((ext_vector_type(4)));

__device__ __forceinline__ f32x4 mfma16(f16x4 a, f16x4 b, f32x4 c) {
    return __builtin_amdgcn_mfma_f32_16x16x16f16(a, b, c, 0, 0, 0);
}

// ---------------- kernel 0: weight prep (fp32 -> fp16, transposed) ----------
__global__ void k_prep(const float* __restrict__ W11, const float* __restrict__ W21,
                       const float* __restrict__ W31, const float* __restrict__ W12,
                       const float* __restrict__ W22, const float* __restrict__ W32,
                       f16* __restrict__ W1t, f16* __restrict__ W2t) {
    int gid = blockIdx.x * 256 + threadIdx.x;
    if (gid < 3 * FIN * FO) {                    // 24576: W1t[m][c][k] = W1[m][k][c]
        int m = gid >> 13, rem = gid & (FIN * FO - 1);
        int k = rem >> 6, c = rem & 63;
        const float* src = m == 0 ? W11 : (m == 1 ? W21 : W31);
        W1t[m * FIN * FO + c * FIN + k] = (f16)src[k * FO + c];
    } else {
        int idx = gid - 3 * FIN * FO;
        if (idx < 3 * FO * FO) {                 // 12288: W2t[m][c][k] = W2[m][k][c]
            int m = idx >> 12, rem = idx & (FO * FO - 1);
            int k = rem >> 6, c = rem & 63;
            const float* src = m == 0 ? W12 : (m == 1 ? W22 : W32);
            W2t[m * FO * FO + c * FO + k] = (f16)src[k * FO + c];
        }
    }
}

// ---------------- kernel 1: fused q/k/v MLPs (MFMA f16) ---------------------
// block = 256 thr (4 waves), each wave does 16 rows; grid = 16384/64 = 256
__global__ __launch_bounds__(256) void k_qkv(
    const float* __restrict__ feat,
    const float* __restrict__ b1q, const float* __restrict__ b2q,
    const float* __restrict__ b1k, const float* __restrict__ b2k,
    const float* __restrict__ b1v, const float* __restrict__ b2v,
    const f16* __restrict__ W1t, const f16* __restrict__ W2t,
    f16* __restrict__ qbuf, f16* __restrict__ kbuf, f16* __restrict__ vtbuf) {
    __shared__ f16 Hs[4][16][68];                // +4 pad
    const int tid = threadIdx.x;
    const int l15 = tid & 15, quad = (tid >> 4) & 3, w = tid >> 6;
    const int row0 = blockIdx.x * 64;            // flat row base (b*N+n)
    const int rbase = row0 + w * 16;
    const int bb = row0 >> 13;                   // batch
    const int n0 = row0 & (NB - 1);

    // X fragments (fp32 -> fp16), 8 k-iters of 16, reused across q/k/v
    f16x4 xf[8];
    const float* xp = feat + (size_t)(rbase + l15) * FIN + quad * 4;
#pragma unroll
    for (int kk = 0; kk < 8; ++kk) {
        float4 t = *(const float4*)(xp + kk * 16);
        f16x4 h; h[0] = (f16)t.x; h[1] = (f16)t.y; h[2] = (f16)t.z; h[3] = (f16)t.w;
        xf[kk] = h;
    }

    for (int m = 0; m < 3; ++m) {
        const float* b1 = m == 0 ? b1q : (m == 1 ? b1k : b1v);
        const float* b2 = m == 0 ? b2q : (m == 1 ? b2k : b2v);
        const f16* w1 = W1t + m * FIN * FO;
        const f16* w2 = W2t + m * FO * FO;

        f32x4 hacc[4] = {};
#pragma unroll
        for (int kk = 0; kk < 8; ++kk) {
#pragma unroll
            for (int nt = 0; nt < 4; ++nt) {
                f16x4 bf = *(const f16x4*)(w1 + (nt * 16 + l15) * FIN + kk * 16 + quad * 4);
                hacc[nt] = mfma16(xf[kk], bf, hacc[nt]);
            }
        }
#pragma unroll
        for (int nt = 0; nt < 4; ++nt) {
            float bv = b1[nt * 16 + l15];
#pragma unroll
            for (int r = 0; r < 4; ++r) {
                float v = hacc[nt][r] + bv;
                Hs[w][quad * 4 + r][nt * 16 + l15] = (f16)(v > 0.f ? v : 0.f);
            }
        }
        __syncthreads();

        f32x4 oacc[4] = {};
#pragma unroll
        for (int kk = 0; kk < 4; ++kk) {
            f16x4 af = *(const f16x4*)(&Hs[w][l15][kk * 16 + quad * 4]);
#pragma unroll
            for (int nt = 0; nt < 4; ++nt) {
                f16x4 bf = *(const f16x4*)(w2 + (nt * 16 + l15) * FO + kk * 16 + quad * 4);
                oacc[nt] = mfma16(af, bf, oacc[nt]);
            }
        }
#pragma unroll
        for (int nt = 0; nt < 4; ++nt) {
            float bv = b2[nt * 16 + l15];
            int col = nt * 16 + l15;
#pragma unroll
            for (int r = 0; r < 4; ++r) {
                float v = oacc[nt][r] + bv;
                f16 hv = (f16)(v > 0.f ? v : 0.f);
                int rl = w * 16 + quad * 4 + r;
                if (m == 0)      qbuf[(size_t)(row0 + rl) * FO + col] = hv;
                else if (m == 1) kbuf[(size_t)(row0 + rl) * FO + col] = hv;
                else             vtbuf[((size_t)bb * FO + col) * NB + n0 + rl] = hv;
            }
        }
        __syncthreads();
    }
}

// ---------------- kernel 2: flash attention (transposed-S trick) ------------
// grid = B * 128 qblocks * SPLIT = 1024; block = 256 (4 waves x 16 q-rows)
__global__ __launch_bounds__(256) void k_attn(
    const float* __restrict__ xw,
    const f16* __restrict__ qbuf, const f16* __restrict__ kbuf,
    const f16* __restrict__ vtbuf,
    float* __restrict__ Obuf, float* __restrict__ mbuf, float* __restrict__ lbuf) {
    const int tid = threadIdx.x;
    const int l15 = tid & 15, quad = (tid >> 4) & 3, w = tid >> 6;
    const int bid = blockIdx.x;
    const int split = bid & (SPLIT - 1);
    const int rest = bid / SPLIT;
    const int qblk = rest & 127;
    const int bb = rest >> 7;
    const int qn = qblk * 64 + w * 16;
    const int kv0 = split * (NB / SPLIT);
    const int NSUP = NB / SPLIT / 64;            // 32 super-tiles of 64 kv

    const f16* qp = qbuf + (size_t)(bb * NB + qn + l15) * FO + quad * 4;
    f16x4 qf[4];
#pragma unroll
    for (int kk = 0; kk < 4; ++kk) qf[kk] = *(const f16x4*)(qp + kk * 16);

    const f16*  kp = kbuf + (size_t)(bb * NB + kv0 + l15) * FO + quad * 4;
    const f16*  vp = vtbuf + (size_t)(bb * FO + l15) * NB + kv0 + quad * 4;
    const float* xwp = xw + (size_t)(bb * NB + qn + l15) * NB + kv0 + quad * 4;

    f32x4 oacc[4] = {};
    float m_run = 0.f, l_run = 0.f;

    f32x4 xwn[4];
#pragma unroll
    for (int st = 0; st < 4; ++st) xwn[st] = *(const f32x4*)(xwp + st * 16);

    for (int sp = 0; sp < NSUP; ++sp) {
        f32x4 xwc[4];
#pragma unroll
        for (int st = 0; st < 4; ++st) xwc[st] = xwn[st];
        int spn = (sp + 1 < NSUP) ? sp + 1 : sp;  // prefetch next xw super-tile
#pragma unroll
        for (int st = 0; st < 4; ++st) xwn[st] = *(const f32x4*)(xwp + spn * 64 + st * 16);

        // S^T = K_tile @ Q^T  -> lane holds S^T[kv=st*16+quad*4+r][q=l15]
        f32x4 s[4];
        const f16* kps = kp + (size_t)sp * 64 * FO;
#pragma unroll
        for (int st = 0; st < 4; ++st) {
            f32x4 acc = {};
            const f16* kpt = kps + st * 16 * FO;
#pragma unroll
            for (int kk = 0; kk < 4; ++kk)
                acc = mfma16(*(const f16x4*)(kpt + kk * 16), qf[kk], acc);
            s[st] = acc;
        }
        // scale by xw, relu, tile max
        float tm = 0.f;
#pragma unroll
        for (int st = 0; st < 4; ++st)
#pragma unroll
            for (int r = 0; r < 4; ++r) {
                float v = s[st][r] * xwc[st][r];
                v = v > 0.f ? v : 0.f;
                s[st][r] = v;
                tm = fmaxf(tm, v);
            }
        tm = fmaxf(tm, __shfl_xor(tm, 16));
        tm = fmaxf(tm, __shfl_xor(tm, 32));
        float m_new = fmaxf(m_run, tm);
        float alpha = __expf(m_run - m_new);
        l_run *= alpha;
#pragma unroll
        for (int dt = 0; dt < 4; ++dt)
#pragma unroll
            for (int r = 0; r < 4; ++r) oacc[dt][r] *= alpha;
        m_run = m_new;

        // P^T in C/D layout == B-operand layout for K=16 MFMA
        f16x4 pf[4];
#pragma unroll
        for (int st = 0; st < 4; ++st) {
            float p0 = __expf(s[st][0] - m_new);
            float p1 = __expf(s[st][1] - m_new);
            float p2 = __expf(s[st][2] - m_new);
            float p3 = __expf(s[st][3] - m_new);
            l_run += (p0 + p1) + (p2 + p3);
            f16x4 h; h[0] = (f16)p0; h[1] = (f16)p1; h[2] = (f16)p2; h[3] = (f16)p3;
            pf[st] = h;
        }
        // O^T += V^T @ P^T
        const f16* vps = vp + sp * 64;
#pragma unroll
        for (int st = 0; st < 4; ++st)
#pragma unroll
            for (int dt = 0; dt < 4; ++dt)
                oacc[dt] = mfma16(*(const f16x4*)(vps + (size_t)dt * 16 * NB + st * 16),
                                  pf[st], oacc[dt]);
    }

    l_run += __shfl_xor(l_run, 16);
    l_run += __shfl_xor(l_run, 32);

    size_t orow = ((size_t)split * BATCH + bb) * NB + qn + l15;
#pragma unroll
    for (int dt = 0; dt < 4; ++dt)
        *(f32x4*)(Obuf + orow * FO + dt * 16 + quad * 4) = oacc[dt];
    if (quad == 0) { mbuf[orow] = m_run; lbuf[orow] = l_run; }
}

// ---------------- kernel 3: combine splits + final relu ---------------------
__global__ void k_comb(const float* __restrict__ Obuf, const float* __restrict__ mbuf,
                       const float* __restrict__ lbuf, float* __restrict__ out) {
    int gid = blockIdx.x * 256 + threadIdx.x;    // < 1048576
    int bn = gid >> 6;
    const int S = BATCH * NB;                    // 16384
    float m0 = mbuf[bn], m1 = mbuf[S + bn], m2 = mbuf[2 * S + bn], m3 = mbuf[3 * S + bn];
    float M = fmaxf(fmaxf(m0, m1), fmaxf(m2, m3));
    float e0 = __expf(m0 - M), e1 = __expf(m1 - M), e2 = __expf(m2 - M), e3 = __expf(m3 - M);
    float L = lbuf[bn] * e0 + lbuf[S + bn] * e1 + lbuf[2 * S + bn] * e2 + lbuf[3 * S + bn] * e3;
    const int ST = S * FO;                       // 1048576
    float o = Obuf[gid] * e0 + Obuf[gid + ST] * e1 + Obuf[gid + 2 * ST] * e2 + Obuf[gid + 3 * ST] * e3;
    float v = o / L;
    out[gid] = v > 0.f ? v : 0.f;
}

// ---------------------------------------------------------------------------
extern "C" void kernel_launch(void* const* d_in, const int* in_sizes, int n_in,
                              void* d_out, int out_size, void* d_ws, size_t ws_size,
                              hipStream_t stream) {
    const float* feat = (const float*)d_in[0];
    const float* xw   = (const float*)d_in[1];
    const float* W11 = (const float*)d_in[2];  const float* b11 = (const float*)d_in[3];
    const float* W12 = (const float*)d_in[4];  const float* b12 = (const float*)d_in[5];
    const float* W21 = (const float*)d_in[6];  const float* b21 = (const float*)d_in[7];
    const float* W22 = (const float*)d_in[8];  const float* b22 = (const float*)d_in[9];
    const float* W31 = (const float*)d_in[10]; const float* b31 = (const float*)d_in[11];
    const float* W32 = (const float*)d_in[12]; const float* b32 = (const float*)d_in[13];

    char* ws = (char*)d_ws;
    f16*   W1t  = (f16*)(ws);                        // 49152 B
    f16*   W2t  = (f16*)(ws + 49152);                // 24576 B
    f16*   qbuf = (f16*)(ws + 73728);                // 2 MB
    f16*   kbuf = (f16*)(ws + 73728 + 2097152);      // 2 MB
    f16*   vtbuf= (f16*)(ws + 73728 + 4194304);      // 2 MB
    float* Obuf = (float*)(ws + 73728 + 6291456);    // 16 MB
    float* mbuf = (float*)(ws + 73728 + 23068672);   // 256 KB
    float* lbuf = (float*)(ws + 73728 + 23330816);   // 256 KB

    k_prep<<<144, 256, 0, stream>>>(W11, W21, W31, W12, W22, W32, W1t, W2t);
    k_qkv<<<256, 256, 0, stream>>>(feat, b11, b12, b21, b22, b31, b32,
                                   W1t, W2t, qbuf, kbuf, vtbuf);
    k_attn<<<BATCH * 128 * SPLIT, 256, 0, stream>>>(xw, qbuf, kbuf, vtbuf,
                                                    Obuf, mbuf, lbuf);
    k_comb<<<4096, 256, 0, stream>>>(Obuf, mbuf, lbuf, (float*)d_out);
}